// Round 2
// baseline (192.006 us; speedup 1.0000x reference)
//
#include <hip/hip_runtime.h>
#include <hip/hip_bf16.h>

#define T 256
#define H 512
#define EPSF 1e-5f

__device__ float block_reduce_sum(float val, float* sbuf) {
    int tid = threadIdx.x;
    sbuf[tid] = val;
    __syncthreads();
    for (int s = 128; s > 0; s >>= 1) {
        if (tid < s) sbuf[tid] += sbuf[tid + s];
        __syncthreads();
    }
    float r = sbuf[0];
    __syncthreads();
    return r;
}

// Z[t][q] = relu(sum_p h[t][p] * U[p][q] + a[q])
__global__ __launch_bounds__(256) void k_gemm_relu(
        const float* __restrict__ h, const float* __restrict__ U,
        const float* __restrict__ a, float* __restrict__ Z) {
    int idx = blockIdx.x * 256 + threadIdx.x;   // t*H + q
    int t = idx >> 9, q = idx & (H - 1);
    float acc = a[q];
    const float* hr = h + t * H;
    for (int p = 0; p < H; ++p)
        acc += hr[p] * U[p * H + q];
    Z[idx] = fmaxf(acc, 0.f);
}

// u0[t][q] = sum_p Z[t][p] * W[p][q] + b[q]
__global__ __launch_bounds__(256) void k_gemm_u0(
        const float* __restrict__ Z, const float* __restrict__ W,
        const float* __restrict__ b, float* __restrict__ u0) {
    int idx = blockIdx.x * 256 + threadIdx.x;
    int t = idx >> 9, q = idx & (H - 1);
    float acc = b[q];
    const float* zr = Z + t * H;
    for (int p = 0; p < H; ++p)
        acc += zr[p] * W[p * H + q];
    u0[idx] = acc;
}

// c[t] = sum_p h[t][p]
__global__ __launch_bounds__(256) void k_row_sum(
        const float* __restrict__ h, float* __restrict__ c) {
    __shared__ float sbuf[256];
    int t = blockIdx.x, tid = threadIdx.x;
    float l = h[t * H + tid] + h[t * H + tid + 256];
    float r = block_reduce_sum(l, sbuf);
    if (tid == 0) c[t] = r;
}

// S[t][q] = sum_{s<=t} h[s][q]  (inclusive prefix over time, per column)
__global__ __launch_bounds__(256) void k_prefix_S(
        const float* __restrict__ h, float* __restrict__ S) {
    int q = blockIdx.x * 256 + threadIdx.x;
    float acc = 0.f;
    for (int t = 0; t < T; ++t) {
        acc += h[t * H + q];
        S[t * H + q] = acc;
    }
}

// Per-row: y = LN(u0; gamma,beta); g = softmax(y) - onehot(tgt); D = LN-backward(g)
__global__ __launch_bounds__(256) void k_compute_d(
        const float* __restrict__ u0, const float* __restrict__ gamma,
        const float* __restrict__ beta, const int* __restrict__ targets,
        float* __restrict__ D) {
    __shared__ float sbuf[256];
    __shared__ float u[H];
    __shared__ float xh[H];
    __shared__ float yv[H];
    int t = blockIdx.x, tid = threadIdx.x;
    const float* ur = u0 + t * H;

    float lsum = 0.f;
    for (int q = tid; q < H; q += 256) { float v = ur[q]; u[q] = v; lsum += v; }
    float m = block_reduce_sum(lsum, sbuf) * (1.f / H);

    float lv = 0.f;
    for (int q = tid; q < H; q += 256) { float d = u[q] - m; lv += d * d; }
    float var = block_reduce_sum(lv, sbuf) * (1.f / H);
    float s = rsqrtf(var + EPSF);

    float lmax = -1e30f;
    for (int q = tid; q < H; q += 256) {
        float x = (u[q] - m) * s;
        xh[q] = x;
        float y = x * gamma[q] + beta[q];
        yv[q] = y;
        lmax = fmaxf(lmax, y);
    }
    sbuf[tid] = lmax; __syncthreads();
    for (int st = 128; st > 0; st >>= 1) {
        if (tid < st) sbuf[tid] = fmaxf(sbuf[tid], sbuf[tid + st]);
        __syncthreads();
    }
    float ymax = sbuf[0]; __syncthreads();

    float lexp = 0.f;
    for (int q = tid; q < H; q += 256) lexp += __expf(yv[q] - ymax);
    float Zs = block_reduce_sum(lexp, sbuf);
    float invZ = 1.f / Zs;
    int tgt = targets[t];

    float l1 = 0.f, l2 = 0.f;
    for (int q = tid; q < H; q += 256) {
        float p = __expf(yv[q] - ymax) * invZ;
        float g = p - (q == tgt ? 1.f : 0.f);
        float gy = g * gamma[q];
        yv[q] = gy;
        l1 += gy;
        l2 += gy * xh[q];
    }
    float mgy = block_reduce_sum(l1, sbuf) * (1.f / H);
    float mgx = block_reduce_sum(l2, sbuf) * (1.f / H);

    for (int q = tid; q < H; q += 256)
        D[t * H + q] = s * (yv[q] - mgy - xh[q] * mgx);
}

// Beta[t][i] = (i<t) ? dot_p(Z[t], h[i]*Z[i]) + c[i] : 0
__global__ __launch_bounds__(256) void k_compute_beta(
        const float* __restrict__ Z, const float* __restrict__ h,
        const float* __restrict__ c, float* __restrict__ Beta) {
    int idx = blockIdx.x * 256 + threadIdx.x;   // t*T + i
    int t = idx >> 8, i = idx & (T - 1);
    if (i >= t) { Beta[idx] = 0.f; return; }
    float acc = 0.f;
    const float* zt = Z + t * H;
    const float* zi = Z + i * H;
    const float* hi = h + i * H;
    for (int p = 0; p < H; ++p)
        acc += zt[p] * hi[p] * zi[p];
    Beta[idx] = acc + c[i];
}

// pre_t[q] = u0 - S_t[q]*sum_{i<t} Beta[t][i]*D[i][q] + sum_{i<t} Beta[t][i]*S[i][q]*D[i][q]
// out = LN(pre; gamma, beta)
__global__ __launch_bounds__(256) void k_finalize(
        const float* __restrict__ u0, const float* __restrict__ D,
        const float* __restrict__ S, const float* __restrict__ Beta,
        const float* __restrict__ gamma, const float* __restrict__ beta,
        float* __restrict__ out) {
    __shared__ float sbuf[256];
    __shared__ float br[T];
    __shared__ float pre[H];
    int t = blockIdx.x, tid = threadIdx.x;

    br[tid] = (tid < t) ? Beta[t * T + tid] : 0.f;
    __syncthreads();

    for (int q = tid; q < H; q += 256) {
        float acc1 = 0.f, acc2 = 0.f;
        for (int i = 0; i < t; ++i) {
            float bdi = br[i] * D[i * H + q];
            acc1 += bdi;
            acc2 += bdi * S[i * H + q];
        }
        pre[q] = u0[t * H + q] - S[t * H + q] * acc1 + acc2;
    }
    __syncthreads();

    float lsum = 0.f;
    for (int q = tid; q < H; q += 256) lsum += pre[q];
    float m = block_reduce_sum(lsum, sbuf) * (1.f / H);
    float lv = 0.f;
    for (int q = tid; q < H; q += 256) { float d = pre[q] - m; lv += d * d; }
    float var = block_reduce_sum(lv, sbuf) * (1.f / H);
    float s = rsqrtf(var + EPSF);
    for (int q = tid; q < H; q += 256) {
        float o = (pre[q] - m) * s * gamma[q] + beta[q];
        out[t * H + q] = o;
    }
}

extern "C" void kernel_launch(void* const* d_in, const int* in_sizes, int n_in,
                              void* d_out, int out_size, void* d_ws, size_t ws_size,
                              hipStream_t stream) {
    const float* h     = (const float*)d_in[0];
    const float* U     = (const float*)d_in[1];
    const float* W     = (const float*)d_in[2];
    const float* a     = (const float*)d_in[3];
    const float* b     = (const float*)d_in[4];
    const float* gamma = (const float*)d_in[5];
    const float* beta  = (const float*)d_in[6];
    const int*   tgt   = (const int*)d_in[7];
    float* out = (float*)d_out;

    float* ws = (float*)d_ws;
    float* Z    = ws;                    // T*H
    float* u0   = Z    + T * H;          // T*H
    float* D    = u0   + T * H;          // T*H
    float* S    = D    + T * H;          // T*H
    float* c    = S    + T * H;          // T
    float* Beta = c    + T;              // T*T

    k_gemm_relu   <<<T * H / 256, 256, 0, stream>>>(h, U, a, Z);
    k_row_sum     <<<T,           256, 0, stream>>>(h, c);
    k_prefix_S    <<<H / 256,     256, 0, stream>>>(h, S);
    k_gemm_u0     <<<T * H / 256, 256, 0, stream>>>(Z, W, b, u0);
    k_compute_d   <<<T,           256, 0, stream>>>(u0, gamma, beta, tgt, D);
    k_compute_beta<<<T * T / 256, 256, 0, stream>>>(Z, h, c, Beta);
    k_finalize    <<<T,           256, 0, stream>>>(u0, D, S, Beta, gamma, beta, out);
}

// Round 3
// 177.749 us; speedup vs baseline: 1.0802x; 1.0802x over previous
//
#include <hip/hip_runtime.h>
#include <hip/hip_bf16.h>

#define T 256
#define H 512
#define EPSF 1e-5f

// block-wide sum over 256 threads: wave shuffle + 4-entry LDS
__device__ __forceinline__ float block_sum(float v, float* s4) {
    for (int o = 32; o; o >>= 1) v += __shfl_xor(v, o);
    int w = threadIdx.x >> 6;
    __syncthreads();
    if ((threadIdx.x & 63) == 0) s4[w] = v;
    __syncthreads();
    return s4[0] + s4[1] + s4[2] + s4[3];
}

__device__ __forceinline__ float block_max(float v, float* s4) {
    for (int o = 32; o; o >>= 1) v = fmaxf(v, __shfl_xor(v, o));
    int w = threadIdx.x >> 6;
    __syncthreads();
    if ((threadIdx.x & 63) == 0) s4[w] = v;
    __syncthreads();
    return fmaxf(fmaxf(s4[0], s4[1]), fmaxf(s4[2], s4[3]));
}

// blocks 0..127: Z = relu(h@U + a) for 2 t-rows each, HZ = h.*Z, c[t] = rowsum(h)
// blocks 128..129: S[t][q] = inclusive prefix over t of h[t][q]
__global__ __launch_bounds__(256) void k_stage1(
        const float* __restrict__ h, const float* __restrict__ U,
        const float* __restrict__ a, float* __restrict__ Z,
        float* __restrict__ HZ, float* __restrict__ c, float* __restrict__ S) {
    int bid = blockIdx.x, tid = threadIdx.x;
    if (bid < 128) {
        __shared__ __align__(16) float sh[1024];   // interleaved: sh[2k+r] = h[t0+r][k]
        __shared__ float s4[4];
        int t0 = bid * 2;
        float2* sh2 = (float2*)sh;
        // stage h rows + row-sum partials
        float p0 = 0.f, p1 = 0.f;
        #pragma unroll
        for (int j = 0; j < 4; ++j) {
            int idx = tid + j * 256;        // 0..1023
            int row = idx >> 9, k = idx & 511;
            float v = h[(t0 + row) * H + k];
            sh[2 * k + row] = v;
            if (row == 0) p0 += v; else p1 += v;
        }
        float sum0 = block_sum(p0, s4);
        float sum1 = block_sum(p1, s4);
        if (tid == 0) { c[t0] = sum0; c[t0 + 1] = sum1; }
        __syncthreads();

        float2 acc0 = {0.f, 0.f}, acc1 = {0.f, 0.f};
        const float2* U2 = (const float2*)U;
        #pragma unroll 8
        for (int k = 0; k < 512; ++k) {
            float2 hh = sh2[k];             // broadcast
            float2 uu = U2[k * 256 + tid];  // coalesced 8B/lane
            acc0.x += hh.x * uu.x; acc0.y += hh.x * uu.y;
            acc1.x += hh.y * uu.x; acc1.y += hh.y * uu.y;
        }
        float2 av = ((const float2*)a)[tid];
        float z00 = fmaxf(acc0.x + av.x, 0.f);
        float z01 = fmaxf(acc0.y + av.y, 0.f);
        float z10 = fmaxf(acc1.x + av.x, 0.f);
        float z11 = fmaxf(acc1.y + av.y, 0.f);
        float4 hv = ((const float4*)sh)[tid]; // {h[t0][2tid],h[t0+1][2tid],h[t0][2tid+1],h[t0+1][2tid+1]}
        float2* Z2 = (float2*)Z;
        float2* HZ2 = (float2*)HZ;
        Z2[t0 * 256 + tid]        = make_float2(z00, z01);
        Z2[(t0 + 1) * 256 + tid]  = make_float2(z10, z11);
        HZ2[t0 * 256 + tid]       = make_float2(hv.x * z00, hv.z * z01);
        HZ2[(t0 + 1) * 256 + tid] = make_float2(hv.y * z10, hv.w * z11);
    } else {
        int q = (bid - 128) * 256 + tid;
        float acc = 0.f;
        for (int t = 0; t < T; ++t) {
            acc += h[t * H + q];
            S[t * H + q] = acc;
        }
    }
}

// u0 = Z@W + b, 2 t-rows per block
__global__ __launch_bounds__(256) void k_stage2(
        const float* __restrict__ Z, const float* __restrict__ W,
        const float* __restrict__ b, float* __restrict__ u0) {
    __shared__ __align__(16) float sh[1024];
    int bid = blockIdx.x, tid = threadIdx.x;
    int t0 = bid * 2;
    float2* sh2 = (float2*)sh;
    #pragma unroll
    for (int j = 0; j < 4; ++j) {
        int idx = tid + j * 256;
        int row = idx >> 9, k = idx & 511;
        sh[2 * k + row] = Z[(t0 + row) * H + k];
    }
    __syncthreads();
    float2 acc0 = {0.f, 0.f}, acc1 = {0.f, 0.f};
    const float2* W2 = (const float2*)W;
    #pragma unroll 8
    for (int k = 0; k < 512; ++k) {
        float2 zz = sh2[k];
        float2 ww = W2[k * 256 + tid];
        acc0.x += zz.x * ww.x; acc0.y += zz.x * ww.y;
        acc1.x += zz.y * ww.x; acc1.y += zz.y * ww.y;
    }
    float2 bv = ((const float2*)b)[tid];
    float2* u2 = (float2*)u0;
    u2[t0 * 256 + tid]       = make_float2(acc0.x + bv.x, acc0.y + bv.y);
    u2[(t0 + 1) * 256 + tid] = make_float2(acc1.x + bv.x, acc1.y + bv.y);
}

// Per-row t: y=LN(u0), g=softmax(y)-onehot, D = LN-backward(g). Row in registers (float2/thread).
__global__ __launch_bounds__(256) void k_compute_d(
        const float* __restrict__ u0, const float* __restrict__ gamma,
        const float* __restrict__ beta, const int* __restrict__ targets,
        float* __restrict__ D) {
    __shared__ float s4[4];
    int t = blockIdx.x, tid = threadIdx.x;
    float2 uv = ((const float2*)u0)[t * 256 + tid];
    float2 gv = ((const float2*)gamma)[tid];
    float2 bv = ((const float2*)beta)[tid];

    float m = block_sum(uv.x + uv.y, s4) * (1.f / H);
    float d0 = uv.x - m, d1 = uv.y - m;
    float var = block_sum(d0 * d0 + d1 * d1, s4) * (1.f / H);
    float s = rsqrtf(var + EPSF);
    float xh0 = d0 * s, xh1 = d1 * s;
    float y0 = xh0 * gv.x + bv.x;
    float y1 = xh1 * gv.y + bv.y;

    float ymax = block_max(fmaxf(y0, y1), s4);
    float e0 = __expf(y0 - ymax), e1 = __expf(y1 - ymax);
    float Zs = block_sum(e0 + e1, s4);
    float invZ = 1.f / Zs;
    int tgt = targets[t];
    int q0 = 2 * tid, q1 = 2 * tid + 1;
    float g0 = e0 * invZ - (q0 == tgt ? 1.f : 0.f);
    float g1 = e1 * invZ - (q1 == tgt ? 1.f : 0.f);
    float gy0 = g0 * gv.x, gy1 = g1 * gv.y;

    float mgy = block_sum(gy0 + gy1, s4) * (1.f / H);
    float mgx = block_sum(gy0 * xh0 + gy1 * xh1, s4) * (1.f / H);

    ((float2*)D)[t * 256 + tid] = make_float2(
        s * (gy0 - mgy - xh0 * mgx),
        s * (gy1 - mgy - xh1 * mgx));
}

// Per t: br[i] = dot(Z[t], HZ[i]) + c[i] (i<t, wave-parallel), then
// pre[q] = u0 - S_t[q]*sum_i br[i]*D[i][q] + sum_i br[i]*S[i][q]*D[i][q]; out = LN(pre)
__global__ __launch_bounds__(256) void k_finalize(
        const float* __restrict__ u0, const float* __restrict__ D,
        const float* __restrict__ S, const float* __restrict__ Z,
        const float* __restrict__ HZ, const float* __restrict__ c,
        const float* __restrict__ gamma, const float* __restrict__ beta,
        float* __restrict__ out) {
    __shared__ __align__(16) float zrow[H];
    __shared__ float br[T];
    __shared__ float s4[4];
    int t = blockIdx.x, tid = threadIdx.x;
    int wid = tid >> 6, lane = tid & 63;

    float2* zrow2 = (float2*)zrow;
    zrow2[tid] = ((const float2*)Z)[t * 256 + tid];
    __syncthreads();

    // Beta row, wave-parallel over i
    for (int i = wid; i < t; i += 4) {
        const float2* hz = (const float2*)(HZ + i * H);
        float acc = 0.f;
        #pragma unroll
        for (int j = 0; j < 4; ++j) {
            int p2 = lane + j * 64;
            float2 v = hz[p2];
            float2 z = zrow2[p2];
            acc += v.x * z.x + v.y * z.y;
        }
        for (int o = 32; o; o >>= 1) acc += __shfl_xor(acc, o);
        if (lane == 0) br[i] = acc + c[i];
    }
    __syncthreads();

    const float2* D2 = (const float2*)D;
    const float2* S2 = (const float2*)S;
    float2 a1 = {0.f, 0.f}, a2 = {0.f, 0.f};
    for (int i = 0; i < t; ++i) {
        float bi = br[i];
        float2 d = D2[i * 256 + tid];
        float2 s = S2[i * 256 + tid];
        float m0 = bi * d.x, m1 = bi * d.y;
        a1.x += m0;        a1.y += m1;
        a2.x += m0 * s.x;  a2.y += m1 * s.y;
    }
    float2 st = S2[t * 256 + tid];
    float2 uv = ((const float2*)u0)[t * 256 + tid];
    float p0 = uv.x - st.x * a1.x + a2.x;
    float p1 = uv.y - st.y * a1.y + a2.y;

    float m = block_sum(p0 + p1, s4) * (1.f / H);
    float d0 = p0 - m, d1 = p1 - m;
    float var = block_sum(d0 * d0 + d1 * d1, s4) * (1.f / H);
    float s = rsqrtf(var + EPSF);
    float2 gv = ((const float2*)gamma)[tid];
    float2 bv = ((const float2*)beta)[tid];
    ((float2*)out)[t * 256 + tid] = make_float2(
        d0 * s * gv.x + bv.x,
        d1 * s * gv.y + bv.y);
}

extern "C" void kernel_launch(void* const* d_in, const int* in_sizes, int n_in,
                              void* d_out, int out_size, void* d_ws, size_t ws_size,
                              hipStream_t stream) {
    const float* h     = (const float*)d_in[0];
    const float* U     = (const float*)d_in[1];
    const float* W     = (const float*)d_in[2];
    const float* a     = (const float*)d_in[3];
    const float* b     = (const float*)d_in[4];
    const float* gamma = (const float*)d_in[5];
    const float* beta  = (const float*)d_in[6];
    const int*   tgt   = (const int*)d_in[7];
    float* out = (float*)d_out;

    float* ws = (float*)d_ws;
    float* Z  = ws;               // T*H
    float* HZ = Z  + T * H;       // T*H
    float* u0 = HZ + T * H;       // T*H
    float* D  = u0 + T * H;       // T*H
    float* S  = D  + T * H;       // T*H
    float* c  = S  + T * H;       // T

    k_stage1   <<<130, 256, 0, stream>>>(h, U, a, Z, HZ, c, S);
    k_stage2   <<<128, 256, 0, stream>>>(Z, W, b, u0);
    k_compute_d<<<T,   256, 0, stream>>>(u0, gamma, beta, tgt, D);
    k_finalize <<<T,   256, 0, stream>>>(u0, D, S, Z, HZ, c, gamma, beta, out);
}

// Round 4
// 146.580 us; speedup vs baseline: 1.3099x; 1.2126x over previous
//
#include <hip/hip_runtime.h>

#define T 256
#define H 512
#define EPSF 1e-5f

__device__ __forceinline__ float block_sum(float v, float* s4) {
    for (int o = 32; o; o >>= 1) v += __shfl_xor(v, o);
    int w = threadIdx.x >> 6;
    __syncthreads();
    if ((threadIdx.x & 63) == 0) s4[w] = v;
    __syncthreads();
    return s4[0] + s4[1] + s4[2] + s4[3];
}

__device__ __forceinline__ float block_max(float v, float* s4) {
    for (int o = 32; o; o >>= 1) v = fmaxf(v, __shfl_xor(v, o));
    int w = threadIdx.x >> 6;
    __syncthreads();
    if ((threadIdx.x & 63) == 0) s4[w] = v;
    __syncthreads();
    return fmaxf(fmaxf(s4[0], s4[1]), fmaxf(s4[2], s4[3]));
}

// bid 0,1: S scan (unroll 8, 16 loads in flight). bid 2..257: Z=relu(h@U+a), HZ=h.*Z, c=rowsum(h).
// GEMM tile: 4 t-rows x 128 q-cols; thread=(c2 0..63, r 0..3): 1 row x 2 cols.
__global__ __launch_bounds__(256) void k1(
        const float* __restrict__ h, const float* __restrict__ U,
        const float* __restrict__ a, float* __restrict__ Z,
        float* __restrict__ HZ, float* __restrict__ c, float* __restrict__ S) {
    int bid = blockIdx.x, tid = threadIdx.x;
    if (bid < 2) {
        int q = bid * 256 + tid;
        float acc = 0.f;
        for (int t0 = 0; t0 < T; t0 += 8) {
            float v[8];
            #pragma unroll
            for (int u = 0; u < 8; ++u) v[u] = h[(t0 + u) * H + q];
            #pragma unroll
            for (int u = 0; u < 8; ++u) { acc += v[u]; S[(t0 + u) * H + q] = acc; }
        }
        return;
    }
    int b = bid - 2;
    int t0 = (b >> 2) * 4;
    int qo = (b & 3) * 128;
    __shared__ __align__(16) float At[4 * H];
    const float4* h4 = (const float4*)(h + t0 * H);
    #pragma unroll
    for (int j = 0; j < 2; ++j) ((float4*)At)[tid + j * 256] = h4[tid + j * 256];
    __syncthreads();

    if ((b & 3) == 0) {                      // c[t0..t0+3], one row per wave
        int w = tid >> 6, lane = tid & 63;
        float s = 0.f;
        #pragma unroll
        for (int j = 0; j < 8; ++j) s += At[w * H + lane + j * 64];
        for (int o = 32; o; o >>= 1) s += __shfl_xor(s, o);
        if (lane == 0) c[t0 + w] = s;
    }

    int c2 = tid & 63, r = tid >> 6;
    int qc = (qo >> 1) + c2;                 // float2 column index
    const float2* U2 = (const float2*)U;
    float accx = 0.f, accy = 0.f;
    for (int k0 = 0; k0 < H; k0 += 8) {
        float2 bv[8];
        #pragma unroll
        for (int u = 0; u < 8; ++u) bv[u] = U2[(k0 + u) * 256 + qc];
        float4 f0 = *(const float4*)&At[r * H + k0];
        float4 f1 = *(const float4*)&At[r * H + k0 + 4];
        float av[8] = {f0.x, f0.y, f0.z, f0.w, f1.x, f1.y, f1.z, f1.w};
        #pragma unroll
        for (int u = 0; u < 8; ++u) { accx += av[u] * bv[u].x; accy += av[u] * bv[u].y; }
    }
    float2 ab = ((const float2*)a)[qc];
    float zx = fmaxf(accx + ab.x, 0.f), zy = fmaxf(accy + ab.y, 0.f);
    float2 hv = ((const float2*)At)[r * 256 + qc];
    int t = t0 + r;
    ((float2*)Z)[t * 256 + qc]  = make_float2(zx, zy);
    ((float2*)HZ)[t * 256 + qc] = make_float2(hv.x * zx, hv.y * zy);
}

// u0 = Z@W + b, same tiling as k1
__global__ __launch_bounds__(256) void k2(
        const float* __restrict__ Z, const float* __restrict__ W,
        const float* __restrict__ bb, float* __restrict__ u0) {
    int bid = blockIdx.x, tid = threadIdx.x;
    int t0 = (bid >> 2) * 4, qo = (bid & 3) * 128;
    __shared__ __align__(16) float At[4 * H];
    const float4* z4 = (const float4*)(Z + t0 * H);
    #pragma unroll
    for (int j = 0; j < 2; ++j) ((float4*)At)[tid + j * 256] = z4[tid + j * 256];
    __syncthreads();
    int c2 = tid & 63, r = tid >> 6;
    int qc = (qo >> 1) + c2;
    const float2* W2 = (const float2*)W;
    float accx = 0.f, accy = 0.f;
    for (int k0 = 0; k0 < H; k0 += 8) {
        float2 bv[8];
        #pragma unroll
        for (int u = 0; u < 8; ++u) bv[u] = W2[(k0 + u) * 256 + qc];
        float4 f0 = *(const float4*)&At[r * H + k0];
        float4 f1 = *(const float4*)&At[r * H + k0 + 4];
        float av[8] = {f0.x, f0.y, f0.z, f0.w, f1.x, f1.y, f1.z, f1.w};
        #pragma unroll
        for (int u = 0; u < 8; ++u) { accx += av[u] * bv[u].x; accy += av[u] * bv[u].y; }
    }
    float2 bv = ((const float2*)bb)[qc];
    int t = t0 + r;
    ((float2*)u0)[t * 256 + qc] = make_float2(accx + bv.x, accy + bv.y);
}

// Per-row t: y=LN(u0), g=softmax(y)-onehot, D=LN-backward(g), SD=S.*D
__global__ __launch_bounds__(256) void k3(
        const float* __restrict__ u0, const float* __restrict__ gamma,
        const float* __restrict__ beta, const int* __restrict__ targets,
        const float* __restrict__ S, float* __restrict__ D, float* __restrict__ SD) {
    __shared__ float s4[4];
    int t = blockIdx.x, tid = threadIdx.x;
    float2 uv = ((const float2*)u0)[t * 256 + tid];
    float2 gv = ((const float2*)gamma)[tid];
    float2 bv = ((const float2*)beta)[tid];

    float m = block_sum(uv.x + uv.y, s4) * (1.f / H);
    float d0 = uv.x - m, d1 = uv.y - m;
    float var = block_sum(d0 * d0 + d1 * d1, s4) * (1.f / H);
    float s = rsqrtf(var + EPSF);
    float xh0 = d0 * s, xh1 = d1 * s;
    float y0 = xh0 * gv.x + bv.x;
    float y1 = xh1 * gv.y + bv.y;

    float ymax = block_max(fmaxf(y0, y1), s4);
    float e0 = __expf(y0 - ymax), e1 = __expf(y1 - ymax);
    float Zs = block_sum(e0 + e1, s4);
    float invZ = 1.f / Zs;
    int tgt = targets[t];
    float g0 = e0 * invZ - (2 * tid == tgt ? 1.f : 0.f);
    float g1 = e1 * invZ - (2 * tid + 1 == tgt ? 1.f : 0.f);
    float gy0 = g0 * gv.x, gy1 = g1 * gv.y;

    float mgy = block_sum(gy0 + gy1, s4) * (1.f / H);
    float mgx = block_sum(gy0 * xh0 + gy1 * xh1, s4) * (1.f / H);

    float dd0 = s * (gy0 - mgy - xh0 * mgx);
    float dd1 = s * (gy1 - mgy - xh1 * mgx);
    float2 sv = ((const float2*)S)[t * 256 + tid];
    ((float2*)D)[t * 256 + tid]  = make_float2(dd0, dd1);
    ((float2*)SD)[t * 256 + tid] = make_float2(sv.x * dd0, sv.y * dd1);
}

// Beta = tril(Z @ HZ^T, -1) + c, tile 4t x 64i, LDS-transpose HZ (pad 129)
__global__ __launch_bounds__(256) void k4(
        const float* __restrict__ Z, const float* __restrict__ HZ,
        const float* __restrict__ c, float* __restrict__ Beta) {
    int bid = blockIdx.x, tid = threadIdx.x;
    int t0 = (bid >> 2) * 4, i0 = (bid & 3) * 64;
    int ci = tid & 63, r = tid >> 6;
    int t = t0 + r, i = i0 + ci;
    if (i0 >= t0 + 3) { Beta[t * 256 + i] = 0.f; return; }  // fully upper tile
    __shared__ float Zt[4][128];
    __shared__ float HT[64][129];
    float acc = 0.f;
    for (int k0 = 0; k0 < H; k0 += 128) {
        __syncthreads();
        #pragma unroll
        for (int j = 0; j < 2; ++j) {
            int idx = tid + j * 256;
            Zt[idx >> 7][idx & 127] = Z[(t0 + (idx >> 7)) * H + k0 + (idx & 127)];
        }
        #pragma unroll
        for (int j = 0; j < 32; ++j) {
            int idx = tid + j * 256;
            HT[idx >> 7][idx & 127] = HZ[(i0 + (idx >> 7)) * H + k0 + (idx & 127)];
        }
        __syncthreads();
        #pragma unroll 8
        for (int k = 0; k < 128; ++k)
            acc += Zt[r][k] * HT[ci][k];
    }
    Beta[t * 256 + i] = (i < t) ? acc + c[i] : 0.f;
}

// A1=Beta@D, A2=Beta@SD (K truncated at t0+4 by triangularity);
// pre = u0 - S_t.*A1 + A2. Tile 4t x 128q.
__global__ __launch_bounds__(256) void k5(
        const float* __restrict__ Beta, const float* __restrict__ D,
        const float* __restrict__ SD, const float* __restrict__ u0,
        const float* __restrict__ S, float* __restrict__ pre) {
    int bid = blockIdx.x, tid = threadIdx.x;
    int t0 = (bid >> 2) * 4, qo = (bid & 3) * 128;
    __shared__ __align__(16) float Bt[4 * 256];
    ((float4*)Bt)[tid] = ((const float4*)(Beta + t0 * 256))[tid];
    __syncthreads();
    int c2 = tid & 63, r = tid >> 6;
    int qc = (qo >> 1) + c2;
    const float2* D2 = (const float2*)D;
    const float2* SD2 = (const float2*)SD;
    float a1x = 0.f, a1y = 0.f, a2x = 0.f, a2y = 0.f;
    int kmax = t0 + 4;
    for (int k0 = 0; k0 < kmax; k0 += 4) {
        float2 dv[4], sv[4]; float bw[4];
        #pragma unroll
        for (int u = 0; u < 4; ++u) {
            dv[u] = D2[(k0 + u) * 256 + qc];
            sv[u] = SD2[(k0 + u) * 256 + qc];
            bw[u] = Bt[r * 256 + k0 + u];
        }
        #pragma unroll
        for (int u = 0; u < 4; ++u) {
            a1x += bw[u] * dv[u].x; a1y += bw[u] * dv[u].y;
            a2x += bw[u] * sv[u].x; a2y += bw[u] * sv[u].y;
        }
    }
    int t = t0 + r;
    float2 uv = ((const float2*)u0)[t * 256 + qc];
    float2 st = ((const float2*)S)[t * 256 + qc];
    ((float2*)pre)[t * 256 + qc] = make_float2(
        uv.x - st.x * a1x + a2x, uv.y - st.y * a1y + a2y);
}

// out = LN(pre; gamma, beta)
__global__ __launch_bounds__(256) void k6(
        const float* __restrict__ pre, const float* __restrict__ gamma,
        const float* __restrict__ beta, float* __restrict__ out) {
    __shared__ float s4[4];
    int t = blockIdx.x, tid = threadIdx.x;
    float2 pv = ((const float2*)pre)[t * 256 + tid];
    float m = block_sum(pv.x + pv.y, s4) * (1.f / H);
    float d0 = pv.x - m, d1 = pv.y - m;
    float var = block_sum(d0 * d0 + d1 * d1, s4) * (1.f / H);
    float s = rsqrtf(var + EPSF);
    float2 gv = ((const float2*)gamma)[tid];
    float2 bv = ((const float2*)beta)[tid];
    ((float2*)out)[t * 256 + tid] = make_float2(
        d0 * s * gv.x + bv.x, d1 * s * gv.y + bv.y);
}

extern "C" void kernel_launch(void* const* d_in, const int* in_sizes, int n_in,
                              void* d_out, int out_size, void* d_ws, size_t ws_size,
                              hipStream_t stream) {
    const float* h     = (const float*)d_in[0];
    const float* U     = (const float*)d_in[1];
    const float* W     = (const float*)d_in[2];
    const float* a     = (const float*)d_in[3];
    const float* b     = (const float*)d_in[4];
    const float* gamma = (const float*)d_in[5];
    const float* beta  = (const float*)d_in[6];
    const int*   tgt   = (const int*)d_in[7];
    float* out = (float*)d_out;

    float* ws = (float*)d_ws;
    float* Z    = ws;              // T*H
    float* HZ   = Z    + T * H;
    float* u0   = HZ   + T * H;
    float* D    = u0   + T * H;
    float* SD   = D    + T * H;
    float* S    = SD   + T * H;
    float* pre  = S    + T * H;
    float* c    = pre  + T * H;    // T
    float* Beta = c    + T;        // T*T

    k1<<<258, 256, 0, stream>>>(h, U, a, Z, HZ, c, S);
    k2<<<256, 256, 0, stream>>>(Z, W, b, u0);
    k3<<<T,   256, 0, stream>>>(u0, gamma, beta, tgt, S, D, SD);
    k4<<<256, 256, 0, stream>>>(Z, HZ, c, Beta);
    k5<<<256, 256, 0, stream>>>(Beta, D, SD, u0, S, pre);
    k6<<<T,   256, 0, stream>>>(pre, gamma, beta, out);
}